// Round 2
// baseline (260.225 us; speedup 1.0000x reference)
//
#include <hip/hip_runtime.h>
#include <stdint.h>

// Problem constants
#define NLAYERS 32
#define DSIZE   1024
#define OSIZE   1024
#define BATCH   32
#define SEQ     256

// ws layout (ints): [0]=nchunks; [16..272)=perm; [512 + 4*c ..]=chunk{layer, rank_base, nranks, pad}
#define WS_PERM  16
#define WS_TILE  512
#define CHUNK    8      // seq positions per m-chunk -> 256 m-rows (8 ranks x 32 batch)
#define MAXC     60     // sum ceil(cnt/8) <= 32 + 28 = 60
#define BK       64
#define TM       256
#define TN       256
#define THREADS  512

typedef __attribute__((ext_vector_type(8)))  short short8;
typedef __attribute__((ext_vector_type(16))) float f32x16;
typedef __attribute__((ext_vector_type(4)))  unsigned uint4v;

__global__ void prep_kernel(const int* __restrict__ layer_idx, int* __restrict__ wsi) {
    __shared__ int cnt[NLAYERS];
    __shared__ int start_[NLAYERS];
    __shared__ int cursor[NLAYERS];
    const int t = threadIdx.x;
    if (t < NLAYERS) cnt[t] = 0;
    __syncthreads();
    int l = 0;
    if (t < SEQ) { l = layer_idx[t]; atomicAdd(&cnt[l], 1); }
    __syncthreads();
    if (t == 0) {
        int acc = 0;
        for (int i = 0; i < NLAYERS; ++i) { start_[i] = acc; cursor[i] = acc; acc += cnt[i]; }
    }
    __syncthreads();
    if (t < SEQ) {
        int r = atomicAdd(&cursor[l], 1);
        wsi[WS_PERM + r] = t;           // perm[rank] = s
    }
    if (t == 0) {
        int nc = 0;
        for (int i = 0; i < NLAYERS; ++i) {
            const int c = cnt[i];
            for (int j = 0; j < c; j += CHUNK) {
                wsi[WS_TILE + nc*4 + 0] = i;
                wsi[WS_TILE + nc*4 + 1] = start_[i] + j;
                wsi[WS_TILE + nc*4 + 2] = (c - j < CHUNK) ? (c - j) : CHUNK;
                ++nc;
            }
        }
        wsi[0] = nc;
    }
}

// round-to-nearest-up fp32->bf16 pair pack: low16 = bf16(a), high16 = bf16(b)
static __device__ __forceinline__ unsigned pk2(float a, float b) {
    unsigned ua = __builtin_bit_cast(unsigned, a) + 0x8000u;
    unsigned ub = __builtin_bit_cast(unsigned, b) + 0x8000u;
    return __builtin_amdgcn_perm(ub, ua, 0x07060302u);  // {ua[2],ua[3],ub[2],ub[3]}
}

// Tile: 256 m-rows (8 ranks x 32 batch) x 256 o-cols, BK=64, 8 waves (4m x 2n),
// wave tile 64m x 128n, acc = 2x4 of 32x32 (128 VGPR).
// LDS: [256][64] bf16 per matrix, XOR-swizzled per 16B granule: granule g of row r
// stored at r*128B + ((g ^ (r&7))*16B)  -> throughput-conflict-free ds_write_b128
// AND ds_read_b128 (each 4-bank group services exactly 8 dwords per wave access).
// Grid: 256 blocks; fid -> (chunk g, ntile n) such that the 4 n-tiles of a chunk share
// an XCD (fid%8 equal) so they share the A-slab in that XCD's L2.
__global__ __launch_bounds__(THREADS, 2) void gemm_kernel(
        const float* __restrict__ x, const float* __restrict__ wgt,
        const int* __restrict__ wsi, float* __restrict__ out) {
    const int fid = blockIdx.x;
    const int g     = (fid & 7) | ((fid >> 5) << 3);   // chunk id 0..63
    const int ntile = (fid >> 3) & 3;                  // o block of 256
    const int nchunks = wsi[0];
    if (g >= nchunks) return;
    const int layer     = wsi[WS_TILE + g*4 + 0];
    const int rank_base = wsi[WS_TILE + g*4 + 1];
    const int nranks    = wsi[WS_TILE + g*4 + 2];      // 1..8

    __shared__ __align__(16) short ldsA[TM * BK];
    __shared__ __align__(16) short ldsB[TN * BK];

    const int t    = threadIdx.x;
    // ---- staging mapping: slot = 16B granule (8 k-elems), row = rb + 64*p
    const int slot = t & 7;
    const int rb   = t >> 3;          // 0..63
    const int wsw  = ((slot ^ (rb & 7)) << 3);   // swizzled granule offset (shorts)

    const float* aptr[4];
    bool av[4];
    #pragma unroll
    for (int p = 0; p < 4; ++p) {
        const int r  = rb + 64*p;
        const int ro = r >> 5;        // rank 0..7
        const int b  = r & 31;        // batch
        av[p] = (ro < nranks);
        const int s = av[p] ? wsi[WS_PERM + rank_base + ro] : 0;
        aptr[p] = x + (((size_t)(b * SEQ + s)) << 10) + slot*8;
    }
    const float* bptr = wgt + ((size_t)layer << 20)
                            + (((size_t)(ntile * TN + rb)) << 10) + slot*8;

    float4 ra[4][2], rbv[4][2];
    auto load_step = [&](int kk) {
        #pragma unroll
        for (int p = 0; p < 4; ++p) {
            if (av[p]) {
                ra[p][0] = *(const float4*)(aptr[p] + kk);
                ra[p][1] = *(const float4*)(aptr[p] + kk + 4);
            }
        }
        #pragma unroll
        for (int p = 0; p < 4; ++p) {
            rbv[p][0] = *(const float4*)(bptr + ((size_t)p << 16) + kk);
            rbv[p][1] = *(const float4*)(bptr + ((size_t)p << 16) + kk + 4);
        }
    };

    // ---- compute mapping: 8 waves as 4(m) x 2(n)
    const int lane = t & 63;
    const int wv   = t >> 6;
    const int l31  = lane & 31;
    const int lh   = lane >> 5;
    const int wm   = (wv >> 1) * 64;   // m base (2 ranks per wave)
    const int wn   = (wv & 1) * 128;   // n base
    const int rsw  = l31 & 7;          // read-side swizzle (row & 7)

    const int baseA0 = (wm +  0 + l31) * BK;
    const int baseA1 = (wm + 32 + l31) * BK;
    int baseB[4];
    #pragma unroll
    for (int ni = 0; ni < 4; ++ni) baseB[ni] = (wn + ni*32 + l31) * BK;

    const int rank0 = wm >> 5;
    const bool ok0 = (rank0 + 0) < nranks;
    const bool ok1 = (rank0 + 1) < nranks;

    f32x16 acc[2][4];
    #pragma unroll
    for (int mi = 0; mi < 2; ++mi)
        #pragma unroll
        for (int ni = 0; ni < 4; ++ni)
            #pragma unroll
            for (int r = 0; r < 16; ++r) acc[mi][ni][r] = 0.f;

    load_step(0);
    #pragma unroll 1
    for (int kk = 0; kk < DSIZE; kk += BK) {
        __syncthreads();   // previous compute done reading LDS
        #pragma unroll
        for (int p = 0; p < 4; ++p) {
            if (av[p]) {
                uint4v u;
                u.x = pk2(ra[p][0].x, ra[p][0].y);
                u.y = pk2(ra[p][0].z, ra[p][0].w);
                u.z = pk2(ra[p][1].x, ra[p][1].y);
                u.w = pk2(ra[p][1].z, ra[p][1].w);
                *(uint4v*)&ldsA[(rb + 64*p) * BK + wsw] = u;
            }
        }
        #pragma unroll
        for (int p = 0; p < 4; ++p) {
            uint4v u;
            u.x = pk2(rbv[p][0].x, rbv[p][0].y);
            u.y = pk2(rbv[p][0].z, rbv[p][0].w);
            u.z = pk2(rbv[p][1].x, rbv[p][1].y);
            u.w = pk2(rbv[p][1].z, rbv[p][1].w);
            *(uint4v*)&ldsB[(rb + 64*p) * BK + wsw] = u;
        }
        __syncthreads();
        if (kk + BK < DSIZE) load_step(kk + BK);  // prefetch overlaps MFMA below
        if (ok0) {
            #pragma unroll
            for (int sub = 0; sub < 4; ++sub) {
                const int gx = (((sub*2 + lh) ^ rsw) << 3);  // swizzled granule (shorts)
                short8 b0[4];
                #pragma unroll
                for (int ni = 0; ni < 4; ++ni)
                    b0[ni] = *(const short8*)&ldsB[baseB[ni] + gx];
                {
                    short8 a0 = *(const short8*)&ldsA[baseA0 + gx];
                    #pragma unroll
                    for (int ni = 0; ni < 4; ++ni)
                        acc[0][ni] = __builtin_amdgcn_mfma_f32_32x32x16_bf16(a0, b0[ni], acc[0][ni], 0, 0, 0);
                }
                if (ok1) {
                    short8 a1 = *(const short8*)&ldsA[baseA1 + gx];
                    #pragma unroll
                    for (int ni = 0; ni < 4; ++ni)
                        acc[1][ni] = __builtin_amdgcn_mfma_f32_32x32x16_bf16(a1, b0[ni], acc[1][ni], 0, 0, 0);
                }
            }
        }
    }

    // epilogue: C/D layout col = lane&31, row = (reg&3) + 8*(reg>>2) + 4*(lane>>5)
    #pragma unroll
    for (int mi = 0; mi < 2; ++mi) {
        const int ro = rank0 + mi;
        if (ro < nranks) {
            const int s = wsi[WS_PERM + rank_base + ro];
            #pragma unroll
            for (int ni = 0; ni < 4; ++ni) {
                const int ocol = ntile * TN + wn + ni*32 + l31;
                #pragma unroll
                for (int r = 0; r < 16; ++r) {
                    const int brow = (r & 3) + 8*(r >> 2) + 4*lh;  // batch b
                    out[(((size_t)(brow * SEQ + s)) << 10) + ocol] = acc[mi][ni][r];
                }
            }
        }
    }
}

extern "C" void kernel_launch(void* const* d_in, const int* in_sizes, int n_in,
                              void* d_out, int out_size, void* d_ws, size_t ws_size,
                              hipStream_t stream) {
    const float* x         = (const float*)d_in[0];
    const int*   layer_idx = (const int*)  d_in[1];
    const float* weight    = (const float*)d_in[2];
    float* out = (float*)d_out;
    int*   wsi = (int*)d_ws;

    prep_kernel<<<1, 256, 0, stream>>>(layer_idx, wsi);
    gemm_kernel<<<256, THREADS, 0, stream>>>(x, weight, wsi, out);
}